// Round 8
// baseline (443.743 us; speedup 1.0000x reference)
//
#include <hip/hip_runtime.h>
#include <cstdint>

constexpr int F        = 128;     // feature width (F_in == H == 128)
constexpr int U_CAP    = 8192;    // cap on |T ∪ in-nbrs(T)|; expected ~2.2k
constexpr int T_CAP    = 128;     // cap on |targets|; actual <= 66
constexpr int BKT      = 128;     // bucket slots per U-node (in-degree ~Poisson(32))
constexpr int BM_WORDS = 3200;    // membership bitmap: supports N <= 102400
constexpr int SBLK     = 256;     // scan block size
constexpr int EPT      = 8;       // edges per thread (round-3 proven: 4-deep ILP)
constexpr int EPBLK    = SBLK * EPT;  // 2048 edges/block -> 1563 blocks at E=3.2M
constexpr int COOP_MAX = 2048;    // fused-scan co-residency cap: 8 blocks/CU x 256 CU

typedef int int4v __attribute__((ext_vector_type(4)));

// hdr: [0]=nT [1]=nU [4]=edge_is_int64 [5]=nbr_is_int64 [8]=barrier [9]=barrier-fail

// XCD-affine bijective chunk swizzle (used by the split-kernel fallback path)
static __device__ __forceinline__ int chunk_of(int b, int nblk) {
    int q = nblk >> 3, r = nblk & 7;
    int xcd = b & 7, idx = b >> 3;
    return (xcd < r) ? xcd * (q + 1) + idx
                     : r * (q + 1) + (xcd - r) * q + idx;
}

__global__ void k_zero(int* p, int n) {
    int i = blockIdx.x * blockDim.x + threadIdx.x;
    int stride = gridDim.x * blockDim.x;
    for (; i < n; i += stride) p[i] = 0;
}

// ---- 1. parallel dedup of targets + int64 detection (one block) ------------
__global__ void k_build(const int* eidx, int E, int N,
                        const int* curr, const int* dest, const int* nbr, int K,
                        int* hdr, int* t_map, int* u_map,
                        unsigned* t_bm, unsigned* u_bm,
                        int* t_node, int* ent2comp, int* ulist) {
    __shared__ int s_e64, s_n64;
    int tid = threadIdx.x;
    if (tid == 0) { s_e64 = 1; s_n64 = 1; }
    __syncthreads();
    if (tid < 64 && eidx[2 * tid + 1] != 0) s_e64 = 0;
    if (tid < K / 2 && nbr[2 * tid + 1] != 0) s_n64 = 0;
    __syncthreads();
    int n64 = s_n64;
    if (tid == 0) { hdr[4] = s_e64; hdr[5] = s_n64; }

    int node = -1;
    if (tid < K + 2) {
        if (tid == 0)      node = curr[0];
        else if (tid == 1) node = dest[0];
        else               node = n64 ? nbr[2 * (tid - 2)] : nbr[tid - 2];
        if ((unsigned)node < (unsigned)N) {
            if (atomicCAS(&t_map[node], 0, -1) == 0) {   // claim: one winner
                int slot = atomicAdd(&hdr[0], 1);
                t_node[slot] = node;
                int uid = atomicAdd(&hdr[1], 1);
                ulist[uid] = node;
                atomicExch(&u_map[node], uid + 1);
                if (node < BM_WORDS * 32) {
                    atomicOr(&t_bm[node >> 5], 1u << (node & 31));
                    atomicOr(&u_bm[node >> 5], 1u << (node & 31));
                }
                atomicExch(&t_map[node], slot + 1);      // publish final slot
            }
        }
    }
    __syncthreads();
    if (tid < K + 2) {
        int v = ((unsigned)node < (unsigned)N) ? atomicAdd(&t_map[node], 0) : 1;
        ent2comp[tid] = v - 1;
    }
}

static __device__ __forceinline__ int esrc(const int* eidx, int E, size_t e, int is64) {
    return is64 ? eidx[2 * e] : eidx[e];
}
static __device__ __forceinline__ int edst(const int* eidx, int E, size_t e, int is64) {
    return is64 ? eidx[2 * ((size_t)E + e)] : eidx[(size_t)E + e];
}

// Issue N independent dwordx4 loads in one asm block; compiler cannot
// serialize it. Latency hides under whatever runs before the matching wait.
static __device__ __forceinline__ void issue4x(const int* p0, const int* p1,
                                               const int* p2, const int* p3,
                                               int4v& a, int4v& b, int4v& c, int4v& d) {
    asm volatile("global_load_dwordx4 %0, %4, off\n\t"
                 "global_load_dwordx4 %1, %5, off\n\t"
                 "global_load_dwordx4 %2, %6, off\n\t"
                 "global_load_dwordx4 %3, %7, off"
                 : "=&v"(a), "=&v"(b), "=&v"(c), "=&v"(d)
                 : "v"(p0), "v"(p1), "v"(p2), "v"(p3));
}
static __device__ __forceinline__ void wait4x(int4v& a, int4v& b, int4v& c, int4v& d) {
    asm volatile("s_waitcnt vmcnt(0)"
                 : "+v"(a), "+v"(b), "+v"(c), "+v"(d));
}
static __device__ __forceinline__ void issue8x(
        const int* p0, const int* p1, const int* p2, const int* p3,
        const int* p4, const int* p5, const int* p6, const int* p7,
        int4v& a0, int4v& a1, int4v& a2, int4v& a3,
        int4v& a4, int4v& a5, int4v& a6, int4v& a7) {
    asm volatile("global_load_dwordx4 %0, %8, off\n\t"
                 "global_load_dwordx4 %1, %9, off\n\t"
                 "global_load_dwordx4 %2, %10, off\n\t"
                 "global_load_dwordx4 %3, %11, off\n\t"
                 "global_load_dwordx4 %4, %12, off\n\t"
                 "global_load_dwordx4 %5, %13, off\n\t"
                 "global_load_dwordx4 %6, %14, off\n\t"
                 "global_load_dwordx4 %7, %15, off"
                 : "=&v"(a0), "=&v"(a1), "=&v"(a2), "=&v"(a3),
                   "=&v"(a4), "=&v"(a5), "=&v"(a6), "=&v"(a7)
                 : "v"(p0), "v"(p1), "v"(p2), "v"(p3),
                   "v"(p4), "v"(p5), "v"(p6), "v"(p7));
}
static __device__ __forceinline__ void wait8x(
        int4v& a0, int4v& a1, int4v& a2, int4v& a3,
        int4v& a4, int4v& a5, int4v& a6, int4v& a7) {
    asm volatile("s_waitcnt vmcnt(0)"
                 : "+v"(a0), "+v"(a1), "+v"(a2), "+v"(a3),
                   "+v"(a4), "+v"(a5), "+v"(a6), "+v"(a7));
}

// ---- 2+3 FUSED: one pass over the dst stream, grid barrier between phases --
// Phase 1 (scan1): probe t_bm, discover U. Phase 2 (scanU): re-probe the SAME
// register-resident d[] against the completed u_bm -> dst stream read ONCE.
// Co-residency: __launch_bounds__(256,8) caps VGPR<=64 -> 8 blocks/CU -> 2048
// slots >= grid (host guarantees grid <= COOP_MAX). Barrier has a bounded spin
// that flags hdr[9] instead of hanging; k_headf folds it into D.
// Coherence: u_map/u_bm are written ONLY via device-scope atomics (coherent
// point) before the barrier; phase 2 reads them with agent-scope atomic loads.
__global__ void __launch_bounds__(SBLK, 8)
k_scan_fused(const int* __restrict__ eidx, int E, int N,
             int* __restrict__ u_map,
             const unsigned* __restrict__ t_bm,
             unsigned* __restrict__ u_bm,
             int* __restrict__ hdr, int* __restrict__ ulist,
             int* __restrict__ deg1, int* __restrict__ bucket) {
    __shared__ unsigned s_bm[BM_WORDS];          // 12.8 KB (t_bm, then u_bm)
    int tid = threadIdx.x;
    int is64 = hdr[4];
    size_t be = (size_t)blockIdx.x * EPBLK;
    bool fast = is64 && ((E & 1) == 0) && be + EPBLK <= (size_t)E;

    int4v va, vb, vc, vd;
    if (fast) {
        const int* ebase = eidx + 2 * ((size_t)E + be);   // dst stream, int64
        issue4x(ebase + (size_t)(0 * SBLK + tid) * 4,
                ebase + (size_t)(1 * SBLK + tid) * 4,
                ebase + (size_t)(2 * SBLK + tid) * 4,
                ebase + (size_t)(3 * SBLK + tid) * 4, va, vb, vc, vd);
    }
    for (int i = tid; i < BM_WORDS / 4; i += SBLK)        // overlaps the loads
        reinterpret_cast<int4*>(s_bm)[i] = reinterpret_cast<const int4*>(t_bm)[i];
    __syncthreads();

    int d[EPT];
    if (fast) {
        wait4x(va, vb, vc, vd);
        d[0] = va.x; d[1] = va.z; d[2] = vb.x; d[3] = vb.z;
        d[4] = vc.x; d[5] = vc.z; d[6] = vd.x; d[7] = vd.z;
        unsigned w[EPT];
        #pragma unroll
        for (int i = 0; i < EPT; ++i) {          // 8 LDS probes, batched
            int dc = ((unsigned)d[i] < (unsigned)N) ? d[i] : 0;
            w[i] = s_bm[dc >> 5];
        }
        unsigned m = 0;
        #pragma unroll
        for (int i = 0; i < EPT; ++i)
            if ((unsigned)d[i] < (unsigned)N && ((w[i] >> (d[i] & 31)) & 1)) m |= 1u << i;
        if (m) {                                 // rare: usually execz-skipped
            #pragma unroll
            for (int i = 0; i < EPT; ++i) if (m & (1u << i)) {
                size_t e = be + (size_t)((i >> 1) * SBLK + tid) * 2 + (i & 1);
                int s = eidx[2 * e];
                if ((unsigned)s < (unsigned)N) {
                    if (atomicCAS(&u_map[s], 0, -1) == 0) {
                        int id = atomicAdd(&hdr[1], 1);
                        if (id < U_CAP) ulist[id] = s;
                        if (s < BM_WORDS * 32) atomicOr(&u_bm[s >> 5], 1u << (s & 31));
                        atomicExch(&u_map[s], id + 1);
                    }
                }
            }
        }
    } else {
        // generic tail / int32 fallback; ALWAYS records d[r] for phase 2
        #pragma unroll
        for (int r = 0; r < EPT; ++r) {
            size_t e = be + (size_t)(r * SBLK + tid);
            int dd = (e < (size_t)E) ? edst(eidx, E, e, is64) : -1;
            d[r] = dd;
            if ((unsigned)dd >= (unsigned)N) continue;
            if (!((s_bm[dd >> 5] >> (dd & 31)) & 1)) continue;
            int s = esrc(eidx, E, e, is64);
            if ((unsigned)s >= (unsigned)N) continue;
            if (atomicCAS(&u_map[s], 0, -1) == 0) {
                int id = atomicAdd(&hdr[1], 1);
                if (id < U_CAP) ulist[id] = s;
                if (s < BM_WORDS * 32) atomicOr(&u_bm[s >> 5], 1u << (s & 31));
                atomicExch(&u_map[s], id + 1);
            }
        }
    }

    // ---- grid-wide barrier (arrive + bounded spin) -------------------------
    __syncthreads();
    if (tid == 0) {
        __threadfence();                         // release phase-1 atomics
        atomicAdd(&hdr[8], 1);
        int spins = 0;
        while (__hip_atomic_load(&hdr[8], __ATOMIC_ACQUIRE,
                                 __HIP_MEMORY_SCOPE_AGENT) < (int)gridDim.x) {
            if (++spins > (1 << 16)) { atomicExch(&hdr[9], 1); break; }
        }
    }
    __syncthreads();

    // ---- phase 2: refill s_bm with completed u_bm; re-probe register d[] ---
    for (int i = tid; i < BM_WORDS; i += SBLK)
        s_bm[i] = __hip_atomic_load(&u_bm[i], __ATOMIC_RELAXED,
                                    __HIP_MEMORY_SCOPE_AGENT);
    __syncthreads();

    unsigned w2[EPT];
    #pragma unroll
    for (int i = 0; i < EPT; ++i) {
        int dc = ((unsigned)d[i] < (unsigned)N) ? d[i] : 0;
        w2[i] = s_bm[dc >> 5];
    }
    unsigned m2 = 0;
    #pragma unroll
    for (int i = 0; i < EPT; ++i)
        if ((unsigned)d[i] < (unsigned)N && ((w2[i] >> (d[i] & 31)) & 1)) m2 |= 1u << i;
    if (m2) {                                    // ~2.2% of edges
        #pragma unroll
        for (int i = 0; i < EPT; ++i) if (m2 & (1u << i)) {
            size_t e = fast ? (be + (size_t)((i >> 1) * SBLK + tid) * 2 + (i & 1))
                            : (be + (size_t)(i * SBLK + tid));
            int umi = __hip_atomic_load(&u_map[d[i]], __ATOMIC_RELAXED,
                                        __HIP_MEMORY_SCOPE_AGENT);
            int s = esrc(eidx, E, e, is64);
            if (umi > 0 && umi <= U_CAP && (unsigned)s < (unsigned)N) {
                int slot = umi - 1;
                int pos = atomicAdd(&deg1[slot], 1);   // scalar atomic, ~2.2k addrs
                if (pos < BKT) bucket[(size_t)slot * BKT + pos] = s;
            }
        }
    }
}

// ---- split-kernel fallback (only if grid would exceed COOP_MAX) ------------
__global__ void k_scan1(const int* __restrict__ eidx, int E, int N,
                        int* __restrict__ u_map,
                        const unsigned* __restrict__ t_bm,
                        unsigned* __restrict__ u_bm,
                        int* __restrict__ hdr, int* __restrict__ ulist) {
    __shared__ unsigned s_bm[BM_WORDS];
    int tid = threadIdx.x;
    int is64 = hdr[4];
    size_t be = (size_t)chunk_of(blockIdx.x, gridDim.x) * EPBLK;
    bool fast = is64 && ((E & 1) == 0) && be + EPBLK <= (size_t)E;

    int4v va, vb, vc, vd;
    if (fast) {
        const int* ebase = eidx + 2 * ((size_t)E + be);
        issue4x(ebase + (size_t)(0 * SBLK + tid) * 4,
                ebase + (size_t)(1 * SBLK + tid) * 4,
                ebase + (size_t)(2 * SBLK + tid) * 4,
                ebase + (size_t)(3 * SBLK + tid) * 4, va, vb, vc, vd);
    }
    for (int i = tid; i < BM_WORDS / 4; i += SBLK)
        reinterpret_cast<int4*>(s_bm)[i] = reinterpret_cast<const int4*>(t_bm)[i];
    __syncthreads();

    if (fast) {
        wait4x(va, vb, vc, vd);
        int d[EPT] = { va.x, va.z, vb.x, vb.z, vc.x, vc.z, vd.x, vd.z };
        unsigned w[EPT];
        #pragma unroll
        for (int i = 0; i < EPT; ++i) {
            int dc = ((unsigned)d[i] < (unsigned)N) ? d[i] : 0;
            w[i] = s_bm[dc >> 5];
        }
        unsigned m = 0;
        #pragma unroll
        for (int i = 0; i < EPT; ++i)
            if ((unsigned)d[i] < (unsigned)N && ((w[i] >> (d[i] & 31)) & 1)) m |= 1u << i;
        if (m) {
            #pragma unroll
            for (int i = 0; i < EPT; ++i) if (m & (1u << i)) {
                size_t e = be + (size_t)((i >> 1) * SBLK + tid) * 2 + (i & 1);
                int s = eidx[2 * e];
                if ((unsigned)s < (unsigned)N) {
                    if (atomicCAS(&u_map[s], 0, -1) == 0) {
                        int id = atomicAdd(&hdr[1], 1);
                        if (id < U_CAP) ulist[id] = s;
                        if (s < BM_WORDS * 32) atomicOr(&u_bm[s >> 5], 1u << (s & 31));
                        atomicExch(&u_map[s], id + 1);
                    }
                }
            }
        }
    } else {
        for (int r = 0; r < EPT; ++r) {
            size_t e = be + (size_t)(r * SBLK + tid);
            if (e >= (size_t)E) continue;
            int dd = edst(eidx, E, e, is64);
            if ((unsigned)dd >= (unsigned)N) continue;
            if (!((s_bm[dd >> 5] >> (dd & 31)) & 1)) continue;
            int s = esrc(eidx, E, e, is64);
            if ((unsigned)s >= (unsigned)N) continue;
            if (atomicCAS(&u_map[s], 0, -1) == 0) {
                int id = atomicAdd(&hdr[1], 1);
                if (id < U_CAP) ulist[id] = s;
                if (s < BM_WORDS * 32) atomicOr(&u_bm[s >> 5], 1u << (s & 31));
                atomicExch(&u_map[s], id + 1);
            }
        }
    }
}

__global__ void k_scanU(const int* __restrict__ eidx, int E, int N,
                        const int* __restrict__ u_map,
                        const unsigned* __restrict__ u_bm,
                        const int* __restrict__ hdr,
                        int* __restrict__ deg1, int* __restrict__ bucket) {
    __shared__ unsigned s_bm[BM_WORDS];
    int tid = threadIdx.x;
    int is64 = hdr[4];
    size_t be = (size_t)chunk_of(blockIdx.x, gridDim.x) * EPBLK;
    bool fast = is64 && ((E & 1) == 0) && be + EPBLK <= (size_t)E;

    int4v va, vb, vc, vd;
    if (fast) {
        const int* ebase = eidx + 2 * ((size_t)E + be);
        issue4x(ebase + (size_t)(0 * SBLK + tid) * 4,
                ebase + (size_t)(1 * SBLK + tid) * 4,
                ebase + (size_t)(2 * SBLK + tid) * 4,
                ebase + (size_t)(3 * SBLK + tid) * 4, va, vb, vc, vd);
    }
    for (int i = tid; i < BM_WORDS / 4; i += SBLK)
        reinterpret_cast<int4*>(s_bm)[i] = reinterpret_cast<const int4*>(u_bm)[i];
    __syncthreads();

    if (fast) {
        wait4x(va, vb, vc, vd);
        int d[EPT] = { va.x, va.z, vb.x, vb.z, vc.x, vc.z, vd.x, vd.z };
        unsigned w[EPT];
        #pragma unroll
        for (int i = 0; i < EPT; ++i) {
            int dc = ((unsigned)d[i] < (unsigned)N) ? d[i] : 0;
            w[i] = s_bm[dc >> 5];
        }
        unsigned m = 0;
        #pragma unroll
        for (int i = 0; i < EPT; ++i)
            if ((unsigned)d[i] < (unsigned)N && ((w[i] >> (d[i] & 31)) & 1)) m |= 1u << i;
        if (m) {
            #pragma unroll
            for (int i = 0; i < EPT; ++i) if (m & (1u << i)) {
                size_t e = be + (size_t)((i >> 1) * SBLK + tid) * 2 + (i & 1);
                int umi = u_map[d[i]];
                int s = eidx[2 * e];
                if (umi > 0 && umi <= U_CAP && (unsigned)s < (unsigned)N) {
                    int slot = umi - 1;
                    int pos = atomicAdd(&deg1[slot], 1);
                    if (pos < BKT) bucket[(size_t)slot * BKT + pos] = s;
                }
            }
        }
    } else {
        for (int r = 0; r < EPT; ++r) {
            size_t e = be + (size_t)(r * SBLK + tid);
            if (e >= (size_t)E) continue;
            int dd = edst(eidx, E, e, is64);
            if ((unsigned)dd >= (unsigned)N) continue;
            if (!((s_bm[dd >> 5] >> (dd & 31)) & 1)) continue;
            int umi = u_map[dd];
            if (umi <= 0 || umi > U_CAP) continue;
            int s = esrc(eidx, E, e, is64);
            if ((unsigned)s >= (unsigned)N) continue;
            int slot = umi - 1;
            int pos = atomicAdd(&deg1[slot], 1);
            if (pos < BKT) bucket[(size_t)slot * BKT + pos] = s;
        }
    }
}

// ---- 4. fused layer-1: asm-ILP bucket gather + GEMV -> h (per U-node) ------
__global__ void k_l1(const int* __restrict__ deg1, const int* __restrict__ bucket,
                     const int* __restrict__ hdr, const int* __restrict__ ulist, int N,
                     const float* __restrict__ x,
                     const float* __restrict__ W1l, const float* __restrict__ W1r,
                     const float* __restrict__ b1, float* __restrict__ h) {
    int nU = min(hdr[1], U_CAP);
    __shared__ int s_src[BKT];
    __shared__ float4 s_part[4][32];
    __shared__ float mean[F];
    __shared__ float xr[F];
    int j = threadIdx.x;   // 128 threads
    int g = j >> 5, l = j & 31;   // 4 row-groups x 32 lanes
    for (int b = blockIdx.x; b < nU; b += gridDim.x) {
        int dg = deg1[b];
        int stored = min(dg, BKT);
        s_src[j] = (j < stored) ? bucket[(size_t)b * BKT + j] : -1;   // pad -1
        int node = ulist[b];
        xr[j] = ((unsigned)node < (unsigned)N) ? x[(size_t)node * F + j] : 0.0f;
        __syncthreads();
        float4 a4 = make_float4(0.f, 0.f, 0.f, 0.f);
        const float* xb = x + 4 * l;
        for (int c = 0; c < stored; c += 32) {
            int s0 = s_src[c + g +  0], s1 = s_src[c + g +  4];
            int s2 = s_src[c + g +  8], s3 = s_src[c + g + 12];
            int s4 = s_src[c + g + 16], s5 = s_src[c + g + 20];
            int s6 = s_src[c + g + 24], s7 = s_src[c + g + 28];
            const float* q0 = xb + (size_t)(s0 >= 0 ? s0 : 0) * F;
            const float* q1 = xb + (size_t)(s1 >= 0 ? s1 : 0) * F;
            const float* q2 = xb + (size_t)(s2 >= 0 ? s2 : 0) * F;
            const float* q3 = xb + (size_t)(s3 >= 0 ? s3 : 0) * F;
            const float* q4 = xb + (size_t)(s4 >= 0 ? s4 : 0) * F;
            const float* q5 = xb + (size_t)(s5 >= 0 ? s5 : 0) * F;
            const float* q6 = xb + (size_t)(s6 >= 0 ? s6 : 0) * F;
            const float* q7 = xb + (size_t)(s7 >= 0 ? s7 : 0) * F;
            int4v r0, r1, r2, r3, r4, r5, r6, r7;
            issue8x((const int*)q0, (const int*)q1, (const int*)q2, (const int*)q3,
                    (const int*)q4, (const int*)q5, (const int*)q6, (const int*)q7,
                    r0, r1, r2, r3, r4, r5, r6, r7);
            wait8x(r0, r1, r2, r3, r4, r5, r6, r7);
            #define ACC4(S, R) if (S >= 0) {                      \
                a4.x += __int_as_float((R).x);                    \
                a4.y += __int_as_float((R).y);                    \
                a4.z += __int_as_float((R).z);                    \
                a4.w += __int_as_float((R).w); }
            ACC4(s0, r0) ACC4(s1, r1) ACC4(s2, r2) ACC4(s3, r3)
            ACC4(s4, r4) ACC4(s5, r5) ACC4(s6, r6) ACC4(s7, r7)
            #undef ACC4
        }
        s_part[g][l] = a4;
        __syncthreads();
        float c = (dg < 1) ? 1.0f : (float)dg;
        int lp = j >> 2, cc = j & 3;
        float sum = 0.0f;
        #pragma unroll
        for (int gg = 0; gg < 4; ++gg) {
            float4 p = s_part[gg][lp];
            sum += (cc == 0) ? p.x : (cc == 1) ? p.y : (cc == 2) ? p.z : p.w;
        }
        mean[j] = sum / c;
        __syncthreads();
        float o1 = b1[j], o2 = 0.0f;           // two chains: shorter dep path
        #pragma unroll 8
        for (int k = 0; k < F; ++k) {
            o1 += mean[k] * W1l[k * F + j];
            o2 += xr[k]   * W1r[k * F + j];
        }
        float o = o1 + o2;
        h[(size_t)b * F + j] = (o > 0.0f) ? o : 0.0f;
        __syncthreads();   // protect LDS before next node
    }
}

// ---- 5. fused layer-2: read target's bucket directly + mean + GEMV ---------
__global__ void k_l2(const int* __restrict__ hdr, const int* __restrict__ t_node,
                     const int* __restrict__ u_map, int N,
                     const int* __restrict__ deg1, const int* __restrict__ bucket,
                     const float* __restrict__ h,
                     const float* __restrict__ W2l, const float* __restrict__ W2r,
                     const float* __restrict__ b2, float* __restrict__ embT) {
    int nT = min(hdr[0], T_CAP);
    int b  = blockIdx.x;
    if (b >= nT) return;
    __shared__ int s_ui[BKT];
    __shared__ float mean[F];
    __shared__ float hr[F];
    int j = threadIdx.x;   // 128 threads
    int node = t_node[b];
    int tui = ((unsigned)node < (unsigned)N) ? (u_map[node] - 1) : -1;
    int dg = 0, stored = 0;
    if ((unsigned)tui < (unsigned)U_CAP) {
        dg = deg1[tui];
        stored = min(dg, BKT);
    }
    if (j < stored) {
        int s  = bucket[(size_t)tui * BKT + j];
        int ui = ((unsigned)s < (unsigned)N) ? (u_map[s] - 1) : -1;
        s_ui[j] = ((unsigned)ui < (unsigned)U_CAP) ? ui : -1;
    }
    hr[j] = ((unsigned)tui < (unsigned)U_CAP) ? h[(size_t)tui * F + j] : 0.0f;
    __syncthreads();
    float sum = 0.0f;
    #pragma unroll 4
    for (int i = 0; i < stored; ++i) {
        int ui = s_ui[i];
        if (ui >= 0) sum += h[(size_t)ui * F + j];
    }
    float c = (dg < 1) ? 1.0f : (float)dg;   // true in-edge count
    mean[j] = sum / c;
    __syncthreads();
    float acc = b2[j];
    #pragma unroll 4
    for (int k = 0; k < F; ++k) {
        acc += mean[k] * W2l[k * F + j];
        acc += hr[k]   * W2r[k * F + j];
    }
    embT[(size_t)b * F + j] = acc;
}

static __device__ __forceinline__ float clamp999(int v) {
    return (float)(v < 0 ? 0 : (v > 999 ? 999 : v));
}

// ---- 6. fused MLP head: full 3F cat @ Wlin1, relu, @ Wlin2 (per k) ---------
__global__ void k_headf(const int* __restrict__ hdr, const int* __restrict__ ent2comp,
                        const float* __restrict__ embT,
                        const float* __restrict__ Wlin1, const float* __restrict__ blin1,
                        const float* __restrict__ Wlin2, const float* __restrict__ blin2,
                        float* __restrict__ out, int K) {
    __shared__ float s_cat[3 * F];
    __shared__ float s_part[4][F];
    __shared__ float red[F];
    int k = blockIdx.x;
    int tid = threadIdx.x;          // 512 threads
    int g = tid >> 7, j = tid & (F - 1);
    int c0 = ent2comp[0] & (T_CAP - 1);
    int c1 = ent2comp[1] & (T_CAP - 1);
    int ck = ent2comp[2 + k] & (T_CAP - 1);
    if (tid < F)          s_cat[tid] = embT[(size_t)c0 * F + tid];
    else if (tid < 2 * F) s_cat[tid] = embT[(size_t)c1 * F + (tid - F)];
    else if (tid < 3 * F) s_cat[tid] = embT[(size_t)ck * F + (tid - 2 * F)];
    __syncthreads();
    float acc = 0.0f;
    #pragma unroll 4
    for (int i = g * 96; i < (g + 1) * 96; ++i)   // 4 groups x 96 = 384 rows
        acc += s_cat[i] * Wlin1[i * F + j];
    s_part[g][j] = acc;
    __syncthreads();
    if (g == 0) {
        float hid = blin1[j] + s_part[0][j] + s_part[1][j] + s_part[2][j] + s_part[3][j];
        hid = (hid > 0.0f) ? hid : 0.0f;
        red[j] = hid * Wlin2[j];
    }
    __syncthreads();
    for (int s = 64; s > 0; s >>= 1) {
        if (tid < s) red[tid] += red[tid + s];
        __syncthreads();
    }
    if (tid == 0) {
        int nT = hdr[0], nU = hdr[1];
        float D = 0.0f;  // inert when every stage count is sane
        if      (nT < 1  || nT > K + 2)  D = 1.0e6f + clamp999(nT) * 1e3f;
        else if (nU < nT || nU > U_CAP)  D = 2.0e6f + clamp999(nU / 10) * 1e3f;
        else if (hdr[9] != 0)            D = 4.0e6f;   // fused-scan barrier failed
        out[k] = red[0] + blin2[0] + D;
    }
}

extern "C" void kernel_launch(void* const* d_in, const int* in_sizes, int n_in,
                              void* d_out, int out_size, void* d_ws, size_t ws_size,
                              hipStream_t stream) {
    const float* x     = (const float*)d_in[0];
    const int*   eidx  = (const int*)d_in[1];
    const int*   curr  = (const int*)d_in[2];
    const int*   dest  = (const int*)d_in[3];
    const int*   nbr   = (const int*)d_in[4];
    const float* W1l   = (const float*)d_in[5];
    const float* W1r   = (const float*)d_in[6];
    const float* b1    = (const float*)d_in[7];
    const float* W2l   = (const float*)d_in[8];
    const float* W2r   = (const float*)d_in[9];
    const float* b2    = (const float*)d_in[10];
    const float* Wlin1 = (const float*)d_in[11];
    const float* blin1 = (const float*)d_in[12];
    const float* Wlin2 = (const float*)d_in[13];
    const float* blin2 = (const float*)d_in[14];
    float* out = (float*)d_out;

    const int N = in_sizes[0] / F;
    const int E = in_sizes[1] / 2;
    const int K = in_sizes[4];

    // ---- workspace layout ----
    char*  ws  = (char*)d_ws;
    size_t off = 0;
    int*      hdr      = (int*)(ws + off);      off += 64;
    int*      t_map    = (int*)(ws + off);      off += (size_t)4 * N;
    int*      u_map    = (int*)(ws + off);      off += (size_t)4 * N;
    int*      t_node   = (int*)(ws + off);      off += (size_t)4 * T_CAP;
    int*      ent2comp = (int*)(ws + off);      off += (size_t)4 * 256;
    int*      ulist    = (int*)(ws + off);      off += (size_t)4 * U_CAP;
    unsigned* t_bm     = (unsigned*)(ws + off); off += (size_t)4 * BM_WORDS;
    unsigned* u_bm     = (unsigned*)(ws + off); off += (size_t)4 * BM_WORDS;
    int*      deg1     = (int*)(ws + off);      off += (size_t)4 * U_CAP;
    size_t zero_bytes = off;                 // everything above starts at 0
    int*      bucket   = (int*)(ws + off);      off += (size_t)4 * U_CAP * BKT;   // 4 MB
    float*    h        = (float*)(ws + off);    off += (size_t)4 * U_CAP * F;     // 4 MB
    float*    embT     = (float*)(ws + off);    off += (size_t)4 * T_CAP * F;

    int zero_words = (int)(zero_bytes / 4);
    k_zero<<<1024, 256, 0, stream>>>((int*)d_ws, zero_words);

    k_build<<<1, 128, 0, stream>>>(eidx, E, N, curr, dest, nbr, K, hdr, t_map, u_map,
                                   t_bm, u_bm, t_node, ent2comp, ulist);

    int sg = (E + EPBLK - 1) / EPBLK;   // 1563 blocks at E=3.2M
    if (sg <= COOP_MAX) {
        // single pass over the dst stream; grid barrier between discovery
        // and bucketing phases (co-residency guaranteed: 8 blocks/CU x 256)
        k_scan_fused<<<sg, SBLK, 0, stream>>>(eidx, E, N, u_map, t_bm, u_bm,
                                              hdr, ulist, deg1, bucket);
    } else {
        k_scan1<<<sg, SBLK, 0, stream>>>(eidx, E, N, u_map, t_bm, u_bm, hdr, ulist);
        k_scanU<<<sg, SBLK, 0, stream>>>(eidx, E, N, u_map, u_bm, hdr, deg1, bucket);
    }
    k_l1<<<2048, 128, 0, stream>>>(deg1, bucket, hdr, ulist, N, x, W1l, W1r, b1, h);
    k_l2<<<T_CAP, 128, 0, stream>>>(hdr, t_node, u_map, N, deg1, bucket, h,
                                    W2l, W2r, b2, embT);
    k_headf<<<K, 512, 0, stream>>>(hdr, ent2comp, embT, Wlin1, blin1, Wlin2, blin2, out, K);
}

// Round 9
// 210.909 us; speedup vs baseline: 2.1040x; 2.1040x over previous
//
#include <hip/hip_runtime.h>
#include <cstdint>

constexpr int F        = 128;     // feature width (F_in == H == 128)
constexpr int U_CAP    = 8192;    // cap on |T ∪ in-nbrs(T)|; expected ~2.2k
constexpr int T_CAP    = 128;     // cap on |targets|; actual <= 66
constexpr int BKT      = 128;     // bucket slots per U-node (in-degree ~Poisson(32))
constexpr int BM_WORDS = 3200;    // membership bitmap: supports N <= 102400
constexpr int SBLK     = 256;     // scan block size
constexpr int EPT      = 8;       // edges per thread (round-3 proven: 4-deep ILP;
                                  // EPT=16/782-blocks regressed (r4); fused grid
                                  // barrier regressed badly (r7, spin-line storm))
constexpr int EPBLK    = SBLK * EPT;  // 2048 edges/block -> 1563 blocks at E=3.2M

typedef int int4v __attribute__((ext_vector_type(4)));

// hdr: [0]=nT [1]=nU [4]=edge_is_int64 [5]=nbr_is_int64

// XCD-affine bijective chunk swizzle (m204 form): blocks with the same
// blockIdx%8 (= same XCD under round-robin dispatch) own a CONTIGUOUS range
// of edge-chunks, identical across both scan kernels (same grid size).
// scan1's dst reads fill XCD-local L2 (3.2 MB/XCD < 4 MB); scanU re-reads
// the same chunk on the same XCD -> L2 hits (~200cy) instead of LLC (~600cy).
// Measured: -6.3 us total (r6). Pure relabeling: correctness unaffected.
static __device__ __forceinline__ int chunk_of(int b, int nblk) {
    int q = nblk >> 3, r = nblk & 7;
    int xcd = b & 7, idx = b >> 3;
    return (xcd < r) ? xcd * (q + 1) + idx
                     : r * (q + 1) + (xcd - r) * q + idx;
}

__global__ void k_zero(int* p, int n) {
    int i = blockIdx.x * blockDim.x + threadIdx.x;
    int stride = gridDim.x * blockDim.x;
    for (; i < n; i += stride) p[i] = 0;
}

// ---- 1. parallel dedup of targets + int64 detection (one block) ------------
__global__ void k_build(const int* eidx, int E, int N,
                        const int* curr, const int* dest, const int* nbr, int K,
                        int* hdr, int* t_map, int* u_map,
                        unsigned* t_bm, unsigned* u_bm,
                        int* t_node, int* ent2comp, int* ulist) {
    __shared__ int s_e64, s_n64;
    int tid = threadIdx.x;
    if (tid == 0) { s_e64 = 1; s_n64 = 1; }
    __syncthreads();
    if (tid < 64 && eidx[2 * tid + 1] != 0) s_e64 = 0;
    if (tid < K / 2 && nbr[2 * tid + 1] != 0) s_n64 = 0;
    __syncthreads();
    int n64 = s_n64;
    if (tid == 0) { hdr[4] = s_e64; hdr[5] = s_n64; }

    int node = -1;
    if (tid < K + 2) {
        if (tid == 0)      node = curr[0];
        else if (tid == 1) node = dest[0];
        else               node = n64 ? nbr[2 * (tid - 2)] : nbr[tid - 2];
        if ((unsigned)node < (unsigned)N) {
            if (atomicCAS(&t_map[node], 0, -1) == 0) {   // claim: one winner
                int slot = atomicAdd(&hdr[0], 1);
                t_node[slot] = node;
                int uid = atomicAdd(&hdr[1], 1);
                ulist[uid] = node;
                atomicExch(&u_map[node], uid + 1);
                if (node < BM_WORDS * 32) {
                    atomicOr(&t_bm[node >> 5], 1u << (node & 31));
                    atomicOr(&u_bm[node >> 5], 1u << (node & 31));
                }
                atomicExch(&t_map[node], slot + 1);      // publish final slot
            }
        }
    }
    __syncthreads();
    if (tid < K + 2) {
        int v = ((unsigned)node < (unsigned)N) ? atomicAdd(&t_map[node], 0) : 1;
        ent2comp[tid] = v - 1;
    }
}

static __device__ __forceinline__ int esrc(const int* eidx, int E, size_t e, int is64) {
    return is64 ? eidx[2 * e] : eidx[e];
}
static __device__ __forceinline__ int edst(const int* eidx, int E, size_t e, int is64) {
    return is64 ? eidx[2 * ((size_t)E + e)] : eidx[(size_t)E + e];
}

// Issue N independent dwordx4 loads in one asm block; compiler cannot
// serialize it. Latency hides under whatever runs before the matching wait.
static __device__ __forceinline__ void issue4x(const int* p0, const int* p1,
                                               const int* p2, const int* p3,
                                               int4v& a, int4v& b, int4v& c, int4v& d) {
    asm volatile("global_load_dwordx4 %0, %4, off\n\t"
                 "global_load_dwordx4 %1, %5, off\n\t"
                 "global_load_dwordx4 %2, %6, off\n\t"
                 "global_load_dwordx4 %3, %7, off"
                 : "=&v"(a), "=&v"(b), "=&v"(c), "=&v"(d)
                 : "v"(p0), "v"(p1), "v"(p2), "v"(p3));
}
static __device__ __forceinline__ void wait4x(int4v& a, int4v& b, int4v& c, int4v& d) {
    asm volatile("s_waitcnt vmcnt(0)"
                 : "+v"(a), "+v"(b), "+v"(c), "+v"(d));
}
static __device__ __forceinline__ void issue8x(
        const int* p0, const int* p1, const int* p2, const int* p3,
        const int* p4, const int* p5, const int* p6, const int* p7,
        int4v& a0, int4v& a1, int4v& a2, int4v& a3,
        int4v& a4, int4v& a5, int4v& a6, int4v& a7) {
    asm volatile("global_load_dwordx4 %0, %8, off\n\t"
                 "global_load_dwordx4 %1, %9, off\n\t"
                 "global_load_dwordx4 %2, %10, off\n\t"
                 "global_load_dwordx4 %3, %11, off\n\t"
                 "global_load_dwordx4 %4, %12, off\n\t"
                 "global_load_dwordx4 %5, %13, off\n\t"
                 "global_load_dwordx4 %6, %14, off\n\t"
                 "global_load_dwordx4 %7, %15, off"
                 : "=&v"(a0), "=&v"(a1), "=&v"(a2), "=&v"(a3),
                   "=&v"(a4), "=&v"(a5), "=&v"(a6), "=&v"(a7)
                 : "v"(p0), "v"(p1), "v"(p2), "v"(p3),
                   "v"(p4), "v"(p5), "v"(p6), "v"(p7));
}
static __device__ __forceinline__ void wait8x(
        int4v& a0, int4v& a1, int4v& a2, int4v& a3,
        int4v& a4, int4v& a5, int4v& a6, int4v& a7) {
    asm volatile("s_waitcnt vmcnt(0)"
                 : "+v"(a0), "+v"(a1), "+v"(a2), "+v"(a3),
                   "+v"(a4), "+v"(a5), "+v"(a6), "+v"(a7));
}

// ---- 2. scan: discover U = T ∪ src(edges into T) ---------------------------
__global__ void k_scan1(const int* __restrict__ eidx, int E, int N,
                        int* __restrict__ u_map,
                        const unsigned* __restrict__ t_bm,
                        unsigned* __restrict__ u_bm,
                        int* __restrict__ hdr, int* __restrict__ ulist) {
    __shared__ unsigned s_bm[BM_WORDS];          // 12.8 KB
    int tid = threadIdx.x;
    int is64 = hdr[4];
    size_t be = (size_t)chunk_of(blockIdx.x, gridDim.x) * EPBLK;
    bool fast = is64 && ((E & 1) == 0) && be + EPBLK <= (size_t)E;

    int4v va, vb, vc, vd;
    if (fast) {
        const int* ebase = eidx + 2 * ((size_t)E + be);   // dst stream, int64
        issue4x(ebase + (size_t)(0 * SBLK + tid) * 4,
                ebase + (size_t)(1 * SBLK + tid) * 4,
                ebase + (size_t)(2 * SBLK + tid) * 4,
                ebase + (size_t)(3 * SBLK + tid) * 4, va, vb, vc, vd);
    }
    for (int i = tid; i < BM_WORDS / 4; i += SBLK)        // overlaps the loads
        reinterpret_cast<int4*>(s_bm)[i] = reinterpret_cast<const int4*>(t_bm)[i];
    __syncthreads();

    if (fast) {
        wait4x(va, vb, vc, vd);
        int d[EPT] = { va.x, va.z, vb.x, vb.z, vc.x, vc.z, vd.x, vd.z };
        unsigned w[EPT];
        #pragma unroll
        for (int i = 0; i < EPT; ++i) {          // 8 LDS probes, batched
            int dc = ((unsigned)d[i] < (unsigned)N) ? d[i] : 0;
            w[i] = s_bm[dc >> 5];
        }
        unsigned m = 0;
        #pragma unroll
        for (int i = 0; i < EPT; ++i)
            if ((unsigned)d[i] < (unsigned)N && ((w[i] >> (d[i] & 31)) & 1)) m |= 1u << i;
        if (m) {                                 // rare: usually execz-skipped
            #pragma unroll
            for (int i = 0; i < EPT; ++i) if (m & (1u << i)) {
                size_t e = be + (size_t)((i >> 1) * SBLK + tid) * 2 + (i & 1);
                int s = eidx[2 * e];
                if ((unsigned)s < (unsigned)N) {
                    if (atomicCAS(&u_map[s], 0, -1) == 0) {
                        int id = atomicAdd(&hdr[1], 1);
                        if (id < U_CAP) ulist[id] = s;
                        if (s < BM_WORDS * 32) atomicOr(&u_bm[s >> 5], 1u << (s & 31));
                        // no fence: u_map/ulist readers are in later kernels
                        atomicExch(&u_map[s], id + 1);
                    }
                }
            }
        }
    } else {
        // generic tail / int32 fallback (covers [be, be+EPBLK) in any order)
        for (int r = 0; r < EPT; ++r) {
            size_t e = be + (size_t)(r * SBLK + tid);
            if (e >= (size_t)E) continue;
            int dd = edst(eidx, E, e, is64);
            if ((unsigned)dd >= (unsigned)N) continue;
            if (!((s_bm[dd >> 5] >> (dd & 31)) & 1)) continue;
            int s = esrc(eidx, E, e, is64);
            if ((unsigned)s >= (unsigned)N) continue;
            if (atomicCAS(&u_map[s], 0, -1) == 0) {
                int id = atomicAdd(&hdr[1], 1);
                if (id < U_CAP) ulist[id] = s;
                if (s < BM_WORDS * 32) atomicOr(&u_bm[s >> 5], 1u << (s & 31));
                atomicExch(&u_map[s], id + 1);
            }
        }
    }
}

// ---- 3. scan: edges into U -> per-dest buckets -----------------------------
// Same chunk swizzle as k_scan1: this block's dst range is L2-resident on
// this XCD from scan1's pass -> L2 hits instead of LLC round trips.
__global__ void k_scanU(const int* __restrict__ eidx, int E, int N,
                        const int* __restrict__ u_map,
                        const unsigned* __restrict__ u_bm,
                        const int* __restrict__ hdr,
                        int* __restrict__ deg1, int* __restrict__ bucket) {
    __shared__ unsigned s_bm[BM_WORDS];          // 12.8 KB
    int tid = threadIdx.x;
    int is64 = hdr[4];
    size_t be = (size_t)chunk_of(blockIdx.x, gridDim.x) * EPBLK;
    bool fast = is64 && ((E & 1) == 0) && be + EPBLK <= (size_t)E;

    int4v va, vb, vc, vd;
    if (fast) {
        const int* ebase = eidx + 2 * ((size_t)E + be);
        issue4x(ebase + (size_t)(0 * SBLK + tid) * 4,
                ebase + (size_t)(1 * SBLK + tid) * 4,
                ebase + (size_t)(2 * SBLK + tid) * 4,
                ebase + (size_t)(3 * SBLK + tid) * 4, va, vb, vc, vd);
    }
    for (int i = tid; i < BM_WORDS / 4; i += SBLK)
        reinterpret_cast<int4*>(s_bm)[i] = reinterpret_cast<const int4*>(u_bm)[i];
    __syncthreads();

    if (fast) {
        wait4x(va, vb, vc, vd);
        int d[EPT] = { va.x, va.z, vb.x, vb.z, vc.x, vc.z, vd.x, vd.z };
        unsigned w[EPT];
        #pragma unroll
        for (int i = 0; i < EPT; ++i) {
            int dc = ((unsigned)d[i] < (unsigned)N) ? d[i] : 0;
            w[i] = s_bm[dc >> 5];
        }
        unsigned m = 0;
        #pragma unroll
        for (int i = 0; i < EPT; ++i)
            if ((unsigned)d[i] < (unsigned)N && ((w[i] >> (d[i] & 31)) & 1)) m |= 1u << i;
        if (m) {                                 // ~2.2% of edges
            #pragma unroll
            for (int i = 0; i < EPT; ++i) if (m & (1u << i)) {
                size_t e = be + (size_t)((i >> 1) * SBLK + tid) * 2 + (i & 1);
                int umi = u_map[d[i]];
                int s = eidx[2 * e];
                if (umi > 0 && umi <= U_CAP && (unsigned)s < (unsigned)N) {
                    int slot = umi - 1;
                    int pos = atomicAdd(&deg1[slot], 1);   // scalar atomic, ~2.2k addrs
                    if (pos < BKT) bucket[(size_t)slot * BKT + pos] = s;
                }
            }
        }
    } else {
        for (int r = 0; r < EPT; ++r) {
            size_t e = be + (size_t)(r * SBLK + tid);
            if (e >= (size_t)E) continue;
            int dd = edst(eidx, E, e, is64);
            if ((unsigned)dd >= (unsigned)N) continue;
            if (!((s_bm[dd >> 5] >> (dd & 31)) & 1)) continue;
            int umi = u_map[dd];
            if (umi <= 0 || umi > U_CAP) continue;
            int s = esrc(eidx, E, e, is64);
            if ((unsigned)s >= (unsigned)N) continue;
            int slot = umi - 1;
            int pos = atomicAdd(&deg1[slot], 1);
            if (pos < BKT) bucket[(size_t)slot * BKT + pos] = s;
        }
    }
}

// ---- 4. fused layer-1: asm-ILP bucket gather + GEMV -> h (per U-node) ------
__global__ void k_l1(const int* __restrict__ deg1, const int* __restrict__ bucket,
                     const int* __restrict__ hdr, const int* __restrict__ ulist, int N,
                     const float* __restrict__ x,
                     const float* __restrict__ W1l, const float* __restrict__ W1r,
                     const float* __restrict__ b1, float* __restrict__ h) {
    int nU = min(hdr[1], U_CAP);
    __shared__ int s_src[BKT];
    __shared__ float4 s_part[4][32];
    __shared__ float mean[F];
    __shared__ float xr[F];
    int j = threadIdx.x;   // 128 threads
    int g = j >> 5, l = j & 31;   // 4 row-groups x 32 lanes
    for (int b = blockIdx.x; b < nU; b += gridDim.x) {
        int dg = deg1[b];
        int stored = min(dg, BKT);
        s_src[j] = (j < stored) ? bucket[(size_t)b * BKT + j] : -1;   // pad -1
        int node = ulist[b];
        xr[j] = ((unsigned)node < (unsigned)N) ? x[(size_t)node * F + j] : 0.0f;
        __syncthreads();
        float4 a4 = make_float4(0.f, 0.f, 0.f, 0.f);
        const float* xb = x + 4 * l;
        for (int c = 0; c < stored; c += 32) {
            int s0 = s_src[c + g +  0], s1 = s_src[c + g +  4];
            int s2 = s_src[c + g +  8], s3 = s_src[c + g + 12];
            int s4 = s_src[c + g + 16], s5 = s_src[c + g + 20];
            int s6 = s_src[c + g + 24], s7 = s_src[c + g + 28];
            const float* q0 = xb + (size_t)(s0 >= 0 ? s0 : 0) * F;
            const float* q1 = xb + (size_t)(s1 >= 0 ? s1 : 0) * F;
            const float* q2 = xb + (size_t)(s2 >= 0 ? s2 : 0) * F;
            const float* q3 = xb + (size_t)(s3 >= 0 ? s3 : 0) * F;
            const float* q4 = xb + (size_t)(s4 >= 0 ? s4 : 0) * F;
            const float* q5 = xb + (size_t)(s5 >= 0 ? s5 : 0) * F;
            const float* q6 = xb + (size_t)(s6 >= 0 ? s6 : 0) * F;
            const float* q7 = xb + (size_t)(s7 >= 0 ? s7 : 0) * F;
            int4v r0, r1, r2, r3, r4, r5, r6, r7;
            issue8x((const int*)q0, (const int*)q1, (const int*)q2, (const int*)q3,
                    (const int*)q4, (const int*)q5, (const int*)q6, (const int*)q7,
                    r0, r1, r2, r3, r4, r5, r6, r7);
            wait8x(r0, r1, r2, r3, r4, r5, r6, r7);
            #define ACC4(S, R) if (S >= 0) {                      \
                a4.x += __int_as_float((R).x);                    \
                a4.y += __int_as_float((R).y);                    \
                a4.z += __int_as_float((R).z);                    \
                a4.w += __int_as_float((R).w); }
            ACC4(s0, r0) ACC4(s1, r1) ACC4(s2, r2) ACC4(s3, r3)
            ACC4(s4, r4) ACC4(s5, r5) ACC4(s6, r6) ACC4(s7, r7)
            #undef ACC4
        }
        s_part[g][l] = a4;
        __syncthreads();
        float c = (dg < 1) ? 1.0f : (float)dg;
        int lp = j >> 2, cc = j & 3;
        float sum = 0.0f;
        #pragma unroll
        for (int gg = 0; gg < 4; ++gg) {
            float4 p = s_part[gg][lp];
            sum += (cc == 0) ? p.x : (cc == 1) ? p.y : (cc == 2) ? p.z : p.w;
        }
        mean[j] = sum / c;
        __syncthreads();
        float o1 = b1[j], o2 = 0.0f;           // two chains: shorter dep path
        #pragma unroll 8
        for (int k = 0; k < F; ++k) {
            o1 += mean[k] * W1l[k * F + j];
            o2 += xr[k]   * W1r[k * F + j];
        }
        float o = o1 + o2;
        h[(size_t)b * F + j] = (o > 0.0f) ? o : 0.0f;
        __syncthreads();   // protect LDS before next node
    }
}

// ---- 5. fused layer-2: read target's bucket directly + mean + GEMV ---------
__global__ void k_l2(const int* __restrict__ hdr, const int* __restrict__ t_node,
                     const int* __restrict__ u_map, int N,
                     const int* __restrict__ deg1, const int* __restrict__ bucket,
                     const float* __restrict__ h,
                     const float* __restrict__ W2l, const float* __restrict__ W2r,
                     const float* __restrict__ b2, float* __restrict__ embT) {
    int nT = min(hdr[0], T_CAP);
    int b  = blockIdx.x;
    if (b >= nT) return;
    __shared__ int s_ui[BKT];
    __shared__ float mean[F];
    __shared__ float hr[F];
    int j = threadIdx.x;   // 128 threads
    int node = t_node[b];
    int tui = ((unsigned)node < (unsigned)N) ? (u_map[node] - 1) : -1;
    int dg = 0, stored = 0;
    if ((unsigned)tui < (unsigned)U_CAP) {
        dg = deg1[tui];
        stored = min(dg, BKT);
    }
    if (j < stored) {
        int s  = bucket[(size_t)tui * BKT + j];
        int ui = ((unsigned)s < (unsigned)N) ? (u_map[s] - 1) : -1;
        s_ui[j] = ((unsigned)ui < (unsigned)U_CAP) ? ui : -1;
    }
    hr[j] = ((unsigned)tui < (unsigned)U_CAP) ? h[(size_t)tui * F + j] : 0.0f;
    __syncthreads();
    float sum = 0.0f;
    #pragma unroll 4
    for (int i = 0; i < stored; ++i) {
        int ui = s_ui[i];
        if (ui >= 0) sum += h[(size_t)ui * F + j];
    }
    float c = (dg < 1) ? 1.0f : (float)dg;   // true in-edge count
    mean[j] = sum / c;
    __syncthreads();
    float acc = b2[j];
    #pragma unroll 4
    for (int k = 0; k < F; ++k) {
        acc += mean[k] * W2l[k * F + j];
        acc += hr[k]   * W2r[k * F + j];
    }
    embT[(size_t)b * F + j] = acc;
}

static __device__ __forceinline__ float clamp999(int v) {
    return (float)(v < 0 ? 0 : (v > 999 ? 999 : v));
}

// ---- 6. fused MLP head: full 3F cat @ Wlin1, relu, @ Wlin2 (per k) ---------
__global__ void k_headf(const int* __restrict__ hdr, const int* __restrict__ ent2comp,
                        const float* __restrict__ embT,
                        const float* __restrict__ Wlin1, const float* __restrict__ blin1,
                        const float* __restrict__ Wlin2, const float* __restrict__ blin2,
                        float* __restrict__ out, int K) {
    __shared__ float s_cat[3 * F];
    __shared__ float s_part[4][F];
    __shared__ float red[F];
    int k = blockIdx.x;
    int tid = threadIdx.x;          // 512 threads
    int g = tid >> 7, j = tid & (F - 1);
    int c0 = ent2comp[0] & (T_CAP - 1);
    int c1 = ent2comp[1] & (T_CAP - 1);
    int ck = ent2comp[2 + k] & (T_CAP - 1);
    if (tid < F)          s_cat[tid] = embT[(size_t)c0 * F + tid];
    else if (tid < 2 * F) s_cat[tid] = embT[(size_t)c1 * F + (tid - F)];
    else if (tid < 3 * F) s_cat[tid] = embT[(size_t)ck * F + (tid - 2 * F)];
    __syncthreads();
    float acc = 0.0f;
    #pragma unroll 4
    for (int i = g * 96; i < (g + 1) * 96; ++i)   // 4 groups x 96 = 384 rows
        acc += s_cat[i] * Wlin1[i * F + j];
    s_part[g][j] = acc;
    __syncthreads();
    if (g == 0) {
        float hid = blin1[j] + s_part[0][j] + s_part[1][j] + s_part[2][j] + s_part[3][j];
        hid = (hid > 0.0f) ? hid : 0.0f;
        red[j] = hid * Wlin2[j];
    }
    __syncthreads();
    for (int s = 64; s > 0; s >>= 1) {
        if (tid < s) red[tid] += red[tid + s];
        __syncthreads();
    }
    if (tid == 0) {
        int nT = hdr[0], nU = hdr[1];
        float D = 0.0f;  // inert when every stage count is sane
        if      (nT < 1  || nT > K + 2)  D = 1.0e6f + clamp999(nT) * 1e3f;
        else if (nU < nT || nU > U_CAP)  D = 2.0e6f + clamp999(nU / 10) * 1e3f;
        out[k] = red[0] + blin2[0] + D;
    }
}

extern "C" void kernel_launch(void* const* d_in, const int* in_sizes, int n_in,
                              void* d_out, int out_size, void* d_ws, size_t ws_size,
                              hipStream_t stream) {
    const float* x     = (const float*)d_in[0];
    const int*   eidx  = (const int*)d_in[1];
    const int*   curr  = (const int*)d_in[2];
    const int*   dest  = (const int*)d_in[3];
    const int*   nbr   = (const int*)d_in[4];
    const float* W1l   = (const float*)d_in[5];
    const float* W1r   = (const float*)d_in[6];
    const float* b1    = (const float*)d_in[7];
    const float* W2l   = (const float*)d_in[8];
    const float* W2r   = (const float*)d_in[9];
    const float* b2    = (const float*)d_in[10];
    const float* Wlin1 = (const float*)d_in[11];
    const float* blin1 = (const float*)d_in[12];
    const float* Wlin2 = (const float*)d_in[13];
    const float* blin2 = (const float*)d_in[14];
    float* out = (float*)d_out;

    const int N = in_sizes[0] / F;
    const int E = in_sizes[1] / 2;
    const int K = in_sizes[4];

    // ---- workspace layout ----
    char*  ws  = (char*)d_ws;
    size_t off = 0;
    int*      hdr      = (int*)(ws + off);      off += 64;
    int*      t_map    = (int*)(ws + off);      off += (size_t)4 * N;
    int*      u_map    = (int*)(ws + off);      off += (size_t)4 * N;
    int*      t_node   = (int*)(ws + off);      off += (size_t)4 * T_CAP;
    int*      ent2comp = (int*)(ws + off);      off += (size_t)4 * 256;
    int*      ulist    = (int*)(ws + off);      off += (size_t)4 * U_CAP;
    unsigned* t_bm     = (unsigned*)(ws + off); off += (size_t)4 * BM_WORDS;
    unsigned* u_bm     = (unsigned*)(ws + off); off += (size_t)4 * BM_WORDS;
    int*      deg1     = (int*)(ws + off);      off += (size_t)4 * U_CAP;
    size_t zero_bytes = off;                 // everything above starts at 0
    int*      bucket   = (int*)(ws + off);      off += (size_t)4 * U_CAP * BKT;   // 4 MB
    float*    h        = (float*)(ws + off);    off += (size_t)4 * U_CAP * F;     // 4 MB
    float*    embT     = (float*)(ws + off);    off += (size_t)4 * T_CAP * F;

    int zero_words = (int)(zero_bytes / 4);
    k_zero<<<1024, 256, 0, stream>>>((int*)d_ws, zero_words);

    k_build<<<1, 128, 0, stream>>>(eidx, E, N, curr, dest, nbr, K, hdr, t_map, u_map,
                                   t_bm, u_bm, t_node, ent2comp, ulist);

    int sg = (E + EPBLK - 1) / EPBLK;   // 1563 blocks; XCD-affine chunk swizzle
    k_scan1<<<sg, SBLK, 0, stream>>>(eidx, E, N, u_map, t_bm, u_bm, hdr, ulist);
    k_scanU<<<sg, SBLK, 0, stream>>>(eidx, E, N, u_map, u_bm, hdr, deg1, bucket);
    k_l1<<<2048, 128, 0, stream>>>(deg1, bucket, hdr, ulist, N, x, W1l, W1r, b1, h);
    k_l2<<<T_CAP, 128, 0, stream>>>(hdr, t_node, u_map, N, deg1, bucket, h,
                                    W2l, W2r, b2, embT);
    k_headf<<<K, 512, 0, stream>>>(hdr, ent2comp, embT, Wlin1, blin1, Wlin2, blin2, out, K);
}